// Round 1
// baseline (421.803 us; speedup 1.0000x reference)
//
#include <hip/hip_runtime.h>

#define BB 4
#define TT 2048
#define CC 768
#define NHH 12
#define HSS 64

typedef __attribute__((ext_vector_type(4))) float floatx4;
typedef __attribute__((ext_vector_type(8))) short shortx8;
typedef __attribute__((ext_vector_type(4))) short shortx4;

union S8u { shortx8 v; struct { shortx4 lo; shortx4 hi; } s; };

__device__ __forceinline__ unsigned short f2bf(float f) {
  union { float f; unsigned int u; } cv; cv.f = f;
  unsigned int u = cv.u;
  u += 0x7FFFu + ((u >> 16) & 1u);   // round-to-nearest-even
  return (unsigned short)(u >> 16);
}

__device__ __forceinline__ shortx8 lds_read8(const short* p) {
  S8u u;
  u.s.lo = *(const shortx4*)p;
  u.s.hi = *(const shortx4*)(p + 4);
  return u.v;
}

// C[M,N] = A[M,K] @ B[K,N] + bias[N]
// A: fp32 or bf16 (row-major), B: fp32 row-major, C: fp32 or bf16.
// 128x128 tile, BK=32, 4 waves (2x2), mfma_f32_16x16x32_bf16.
// LDS stride 36 shorts (72B): b64 reads and transposed-B writes conflict-free.
template<bool A_BF16, bool OUT_BF16>
__global__ __launch_bounds__(256)
void gemm_bias_kernel(const void* __restrict__ Ap, const float* __restrict__ Bp,
                      const float* __restrict__ bias, void* __restrict__ Cp,
                      int M, int N, int K) {
  constexpr int STR = 36;
  __shared__ short As[128 * STR];
  __shared__ short Bs[128 * STR];   // transposed: Bs[n][k]

  const int tid = threadIdx.x;
  const int lane = tid & 63;
  const int wave = tid >> 6;
  const int wm = (wave >> 1) * 64;
  const int wn = (wave & 1) * 64;
  const int row = lane & 15;
  const int quad = lane >> 4;
  const int m0 = blockIdx.x * 128;
  const int n0 = blockIdx.y * 128;

  floatx4 acc[4][4];
#pragma unroll
  for (int i = 0; i < 4; ++i)
#pragma unroll
    for (int j = 0; j < 4; ++j) acc[i][j] = (floatx4)(0.0f);

  const int ar = tid >> 3;          // 0..31 (A row group)
  const int ac = (tid & 7) * 4;     // 0..28 (A col)
  const int bn = tid & 127;         // 0..127 (B col)
  const int bk0 = (tid >> 7) * 4;   // 0 or 4

  for (int k0 = 0; k0 < K; k0 += 32) {
    // ---- stage A tile (128 x 32) as bf16 ----
    if (A_BF16) {
      const unsigned short* A = (const unsigned short*)Ap;
#pragma unroll
      for (int it = 0; it < 4; ++it) {
        const int r = ar + it * 32;
        shortx4 v = *(const shortx4*)(A + (size_t)(m0 + r) * K + k0 + ac);
        *(shortx4*)&As[r * STR + ac] = v;
      }
    } else {
      const float* A = (const float*)Ap;
#pragma unroll
      for (int it = 0; it < 4; ++it) {
        const int r = ar + it * 32;
        float4 v = *(const float4*)(A + (size_t)(m0 + r) * K + k0 + ac);
        shortx4 s;
        s.x = (short)f2bf(v.x); s.y = (short)f2bf(v.y);
        s.z = (short)f2bf(v.z); s.w = (short)f2bf(v.w);
        *(shortx4*)&As[r * STR + ac] = s;
      }
    }
    // ---- stage B tile (32 x 128) transposed into Bs[n][k] ----
    // 4 k-consecutive scalar loads per thread (each instr coalesced across lanes)
#pragma unroll
    for (int it = 0; it < 4; ++it) {
      const int kk = bk0 + it * 8;
      const float* bp = Bp + (size_t)(k0 + kk) * N + n0 + bn;
      const float v0 = bp[0];
      const float v1 = bp[(size_t)N];
      const float v2 = bp[(size_t)2 * N];
      const float v3 = bp[(size_t)3 * N];
      shortx4 s;
      s.x = (short)f2bf(v0); s.y = (short)f2bf(v1);
      s.z = (short)f2bf(v2); s.w = (short)f2bf(v3);
      *(shortx4*)&Bs[bn * STR + kk] = s;
    }
    __syncthreads();

    shortx8 af[4], bfr[4];
#pragma unroll
    for (int g = 0; g < 4; ++g) {
      af[g]  = lds_read8(&As[(wm + g * 16 + row) * STR + quad * 8]);
      bfr[g] = lds_read8(&Bs[(wn + g * 16 + row) * STR + quad * 8]);
    }
#pragma unroll
    for (int mg = 0; mg < 4; ++mg)
#pragma unroll
      for (int ng = 0; ng < 4; ++ng)
        acc[mg][ng] = __builtin_amdgcn_mfma_f32_16x16x32_bf16(af[mg], bfr[ng], acc[mg][ng], 0, 0, 0);
    __syncthreads();
  }

  // epilogue: D row = quad*4 + reg, col = lane&15  (verified C/D mapping)
#pragma unroll
  for (int mg = 0; mg < 4; ++mg) {
    const int m = m0 + wm + mg * 16 + quad * 4;
#pragma unroll
    for (int ng = 0; ng < 4; ++ng) {
      const int n = n0 + wn + ng * 16 + row;
      const float bv = bias[n];
#pragma unroll
      for (int r = 0; r < 4; ++r) {
        const float val = acc[mg][ng][r] + bv;
        if (OUT_BF16) {
          ((unsigned short*)Cp)[(size_t)(m + r) * N + n] = f2bf(val);
        } else {
          ((float*)Cp)[(size_t)(m + r) * N + n] = val;
        }
      }
    }
  }
}

// Flash attention. Block = 4 waves; block handles 64 queries of one (b,h);
// wave w owns queries [qt*64 + w*16, +16). K-tile = 64 keys.
// qkv layout: [B*T, 3C] bf16 (q at +0, k at +C, v at +2C within a row).
__global__ __launch_bounds__(256)
void attn_kernel(const unsigned short* __restrict__ qkv, unsigned short* __restrict__ y) {
  constexpr int KSTR = 72;  // Ks[key][d], 16B-aligned rows
  constexpr int VSTR = 68;  // Vs[d][key] (transposed), 8B-aligned rows
  constexpr int PSTR = 72;  // per-wave P scratch [16][64]
  __shared__ short Ks[64 * KSTR];
  __shared__ short Vs[64 * VSTR];
  __shared__ short Ps[4][16 * PSTR];

  const int qt = blockIdx.x;
  const int h = blockIdx.y;
  const int b = blockIdx.z;
  const int tid = threadIdx.x;
  const int lane = tid & 63;
  const int wave = tid >> 6;
  const int row = lane & 15;
  const int quad = lane >> 4;

  const int q_base = qt * 64 + wave * 16;
  const size_t bt0 = (size_t)b * TT * (3 * CC);

  // Q fragments (A-operand layout: A[m=lane&15][k=quad*8+j]), HS=64 -> 2 chunks
  shortx8 qf0, qf1;
  {
    const unsigned short* qp = qkv + bt0 + (size_t)(q_base + row) * (3 * CC) + h * HSS;
    qf0 = *(const shortx8*)(qp + quad * 8);
    qf1 = *(const shortx8*)(qp + 32 + quad * 8);
  }

  float m_r[4], l_r[4];
  floatx4 o_acc[4];
#pragma unroll
  for (int r = 0; r < 4; ++r) { m_r[r] = -1e30f; l_r[r] = 0.0f; }
#pragma unroll
  for (int g = 0; g < 4; ++g) o_acc[g] = (floatx4)(0.0f);

  const int skey = tid >> 3;        // 0..31
  const int sdg = (tid & 7) * 8;    // 0..56

  for (int kt = 0; kt <= qt; ++kt) {
    __syncthreads();   // previous iteration's LDS reads done before restaging
    // ---- stage K [key][d] and V transposed [d][key] ----
#pragma unroll
    for (int it = 0; it < 2; ++it) {
      const int key = skey + it * 32;
      const unsigned short* kp = qkv + bt0 + (size_t)(kt * 64 + key) * (3 * CC) + CC + h * HSS + sdg;
      *(shortx8*)&Ks[key * KSTR + sdg] = *(const shortx8*)kp;
      shortx8 vv = *(const shortx8*)(kp + CC);
#pragma unroll
      for (int j = 0; j < 8; ++j)
        Vs[(sdg + j) * VSTR + key] = vv[j];
    }
    __syncthreads();

    // ---- S = (Q @ K^T) * 1/sqrt(HS); B-operand: B[k=quad*8+j][n=lane&15] ----
    floatx4 s_acc[4];
#pragma unroll
    for (int n = 0; n < 4; ++n) {
      shortx8 kf0 = lds_read8(&Ks[(n * 16 + row) * KSTR + quad * 8]);
      shortx8 kf1 = lds_read8(&Ks[(n * 16 + row) * KSTR + 32 + quad * 8]);
      floatx4 t = __builtin_amdgcn_mfma_f32_16x16x32_bf16(qf0, kf0, (floatx4)(0.0f), 0, 0, 0);
      s_acc[n] = __builtin_amdgcn_mfma_f32_16x16x32_bf16(qf1, kf1, t, 0, 0, 0);
    }

    float sc[4][4];
#pragma unroll
    for (int n = 0; n < 4; ++n)
#pragma unroll
      for (int r = 0; r < 4; ++r) sc[n][r] = s_acc[n][r] * 0.125f;

    if (kt == qt) {  // only the diagonal tile needs the causal mask
#pragma unroll
      for (int n = 0; n < 4; ++n) {
        const int key = n * 16 + row;                    // within tile
#pragma unroll
        for (int r = 0; r < 4; ++r) {
          const int query = wave * 16 + quad * 4 + r;    // within tile
          if (key > query) sc[n][r] = -1e30f;
        }
      }
    }

    // ---- online softmax; row quad*4+r spread over the quad's 16 lanes ----
    float rmax[4];
#pragma unroll
    for (int r = 0; r < 4; ++r)
      rmax[r] = fmaxf(fmaxf(sc[0][r], sc[1][r]), fmaxf(sc[2][r], sc[3][r]));
#pragma unroll
    for (int off = 1; off < 16; off <<= 1)
#pragma unroll
      for (int r = 0; r < 4; ++r)
        rmax[r] = fmaxf(rmax[r], __shfl_xor(rmax[r], off));

    float alpha[4];
#pragma unroll
    for (int r = 0; r < 4; ++r) {
      const float mn = fmaxf(m_r[r], rmax[r]);
      alpha[r] = __expf(m_r[r] - mn);
      m_r[r] = mn;
    }
    float p[4][4];
#pragma unroll
    for (int n = 0; n < 4; ++n)
#pragma unroll
      for (int r = 0; r < 4; ++r) p[n][r] = __expf(sc[n][r] - m_r[r]);

    float rsum[4];
#pragma unroll
    for (int r = 0; r < 4; ++r) rsum[r] = (p[0][r] + p[1][r]) + (p[2][r] + p[3][r]);
#pragma unroll
    for (int off = 1; off < 16; off <<= 1)
#pragma unroll
      for (int r = 0; r < 4; ++r) rsum[r] += __shfl_xor(rsum[r], off);

#pragma unroll
    for (int r = 0; r < 4; ++r) l_r[r] = l_r[r] * alpha[r] + rsum[r];
#pragma unroll
    for (int g = 0; g < 4; ++g) {
      floatx4 t = o_acc[g];
      t[0] *= alpha[0]; t[1] *= alpha[1]; t[2] *= alpha[2]; t[3] *= alpha[3];
      o_acc[g] = t;
    }

    // ---- P: C-layout -> LDS -> A-layout (bf16) ----
    short* pw = &Ps[wave][0];
#pragma unroll
    for (int n = 0; n < 4; ++n)
#pragma unroll
      for (int r = 0; r < 4; ++r)
        pw[(quad * 4 + r) * PSTR + n * 16 + row] = (short)f2bf(p[n][r]);

    __syncthreads();   // conservative: guarantees P writes visible cross-lane

    // ---- O += P @ V ----
#pragma unroll
    for (int c = 0; c < 2; ++c) {
      shortx8 pf = lds_read8(&Ps[wave][row * PSTR + c * 32 + quad * 8]);
#pragma unroll
      for (int g = 0; g < 4; ++g) {
        shortx8 vf = lds_read8(&Vs[(g * 16 + row) * VSTR + c * 32 + quad * 8]);
        o_acc[g] = __builtin_amdgcn_mfma_f32_16x16x32_bf16(pf, vf, o_acc[g], 0, 0, 0);
      }
    }
  }

  // epilogue: y[b,t,h*64+d] bf16
#pragma unroll
  for (int r = 0; r < 4; ++r) {
    const float inv = 1.0f / l_r[r];
    const size_t orow = ((size_t)b * TT + q_base + quad * 4 + r) * CC + h * HSS;
#pragma unroll
    for (int g = 0; g < 4; ++g)
      y[orow + g * 16 + row] = f2bf(o_acc[g][r] * inv);
  }
}

extern "C" void kernel_launch(void* const* d_in, const int* in_sizes, int n_in,
                              void* d_out, int out_size, void* d_ws, size_t ws_size,
                              hipStream_t stream) {
  const float* x      = (const float*)d_in[0];
  const float* w_attn = (const float*)d_in[1];
  const float* b_attn = (const float*)d_in[2];
  const float* w_proj = (const float*)d_in[3];
  const float* b_proj = (const float*)d_in[4];
  float* out = (float*)d_out;

  // workspace: qkv bf16 [8192, 2304] then y bf16 [8192, 768]  (48 MiB total)
  unsigned short* qkv = (unsigned short*)d_ws;
  unsigned short* y   = (unsigned short*)((char*)d_ws + (size_t)BB * TT * 3 * CC * 2);

  const int M = BB * TT;  // 8192
  gemm_bias_kernel<false, true><<<dim3(M / 128, (3 * CC) / 128), 256, 0, stream>>>(
      (const void*)x, w_attn, b_attn, (void*)qkv, M, 3 * CC, CC);
  attn_kernel<<<dim3(TT / 64, NHH, BB), 256, 0, stream>>>(qkv, y);
  gemm_bias_kernel<true, false><<<dim3(M / 128, CC / 128), 256, 0, stream>>>(
      (const void*)y, w_proj, b_proj, (void*)out, M, CC, CC);
}

// Round 2
// 336.003 us; speedup vs baseline: 1.2554x; 1.2554x over previous
//
#include <hip/hip_runtime.h>

#define BB 4
#define TT 2048
#define CC 768
#define QKVW 2304          // 3*CC
#define NHH 12
#define HSS 64

typedef __attribute__((ext_vector_type(4))) float floatx4;
typedef __attribute__((ext_vector_type(8))) short shortx8;
typedef __attribute__((ext_vector_type(4))) short shortx4;

__device__ __forceinline__ unsigned short f2bf(float f) {  // RNE
  union { float f; unsigned int u; } cv; cv.f = f;
  unsigned int u = cv.u;
  u += 0x7FFFu + ((u >> 16) & 1u);
  return (unsigned short)(u >> 16);
}
__device__ __forceinline__ unsigned short bfp(float f) {   // round-half-up (cheap, unbiased enough)
  union { float f; unsigned int u; } cv; cv.f = f;
  return (unsigned short)((cv.u + 0x8000u) >> 16);
}

// DPP rotate within 16-lane rows: VALU pipe, not LDS (replaces __shfl_xor)
template<int C>
__device__ __forceinline__ float dppf(float x) {
  int i = __builtin_bit_cast(int, x);
  return __builtin_bit_cast(float, __builtin_amdgcn_update_dpp(i, i, C, 0xF, 0xF, false));
}
__device__ __forceinline__ float rowmax16(float x) {
  x = fmaxf(x, dppf<0x121>(x));  // row_ror:1
  x = fmaxf(x, dppf<0x122>(x));  // row_ror:2
  x = fmaxf(x, dppf<0x124>(x));  // row_ror:4
  x = fmaxf(x, dppf<0x128>(x));  // row_ror:8
  return x;
}
__device__ __forceinline__ float rowsum16(float x) {
  x += dppf<0x121>(x); x += dppf<0x122>(x); x += dppf<0x124>(x); x += dppf<0x128>(x);
  return x;
}

// async global->LDS, 16B per lane; LDS dest = wave-uniform base + lane*16
__device__ __forceinline__ void async_copy16(const void* g, void* l) {
  __builtin_amdgcn_global_load_lds(
      (const __attribute__((address_space(1))) unsigned int*)g,
      (__attribute__((address_space(3))) unsigned int*)l, 16, 0, 0);
}

// ---------- prep kernels ----------
__global__ void convert_x(const float* __restrict__ x, unsigned short* __restrict__ xb, int n4) {
  int i = blockIdx.x * blockDim.x + threadIdx.x;
  const int stride = gridDim.x * blockDim.x;
  for (; i < n4; i += stride) {
    float4 v = ((const float4*)x)[i];
    shortx4 s;
    s.x = (short)f2bf(v.x); s.y = (short)f2bf(v.y);
    s.z = (short)f2bf(v.z); s.w = (short)f2bf(v.w);
    ((shortx4*)xb)[i] = s;
  }
}

// w[K][N] fp32 -> wt[N][K] bf16 ; grid (N/64, K/64)
__global__ __launch_bounds__(256)
void transpose_w(const float* __restrict__ w, unsigned short* __restrict__ wt, int K, int N) {
  __shared__ short tile[64 * 68];
  const int n0 = blockIdx.x * 64, k0 = blockIdx.y * 64;
  const int tid = threadIdx.x;
  {
    const int tr = tid >> 4, tc = (tid & 15) * 4;
#pragma unroll
    for (int i = 0; i < 4; ++i) {
      float4 v = *(const float4*)(w + (size_t)(k0 + tr + 16 * i) * N + n0 + tc);
      short* d = &tile[(tr + 16 * i) * 68 + tc];
      d[0] = (short)f2bf(v.x); d[1] = (short)f2bf(v.y);
      d[2] = (short)f2bf(v.z); d[3] = (short)f2bf(v.w);
    }
  }
  __syncthreads();
  {
    const int wr = tid >> 3, wc = (tid & 7) * 8;
#pragma unroll
    for (int j = 0; j < 2; ++j) {
      const int n = wr + 32 * j;
      shortx8 s;
#pragma unroll
      for (int e = 0; e < 8; ++e) s[e] = tile[(wc + e) * 68 + n];
      *(shortx8*)(wt + (size_t)(n0 + n) * K + k0 + wc) = s;
    }
  }
}

// V part of qkv -> Vt[bh][d][t] bf16 ; grid (T/64, B*NH)
__global__ __launch_bounds__(256)
void transpose_v(const unsigned short* __restrict__ qkv, unsigned short* __restrict__ Vt) {
  __shared__ short tile[64 * 72];   // [t'][d]
  const int t0 = blockIdx.x * 64;
  const int bh = blockIdx.y;
  const int b = bh / NHH, h = bh % NHH;
  const int tid = threadIdx.x;
  {
    const int tr = tid >> 3, tc = (tid & 7) * 8;
#pragma unroll
    for (int i = 0; i < 2; ++i) {
      shortx8 v = *(const shortx8*)(qkv + ((size_t)(b * TT + t0 + tr + 32 * i)) * QKVW + 2 * CC + h * HSS + tc);
      *(shortx8*)&tile[(tr + 32 * i) * 72 + tc] = v;
    }
  }
  __syncthreads();
  {
    const int dr = tid >> 3, tc = (tid & 7) * 8;
#pragma unroll
    for (int j = 0; j < 2; ++j) {
      const int d = dr + 32 * j;
      shortx8 s;
#pragma unroll
      for (int e = 0; e < 8; ++e) s[e] = tile[(tc + e) * 72 + d];
      *(shortx8*)(Vt + ((size_t)bh * HSS + d) * TT + t0 + tc) = s;
    }
  }
}

// ---------- GEMM (m97 structure): C = A[M,K]bf16 @ Bt[N,K]bf16^T + bias ----------
template<bool OUT_BF16, bool QSCALE>
__global__ __launch_bounds__(256)
void gemm_tn(const unsigned short* __restrict__ A, const unsigned short* __restrict__ Bt,
             const float* __restrict__ bias, void* __restrict__ Cp, int M, int N, int K) {
  __shared__ short As[128 * 32];
  __shared__ short Bs[128 * 32];
  const int tid = threadIdx.x, lane = tid & 63, wave = tid >> 6;
  const int row = lane & 15, quad = lane >> 4;
  const int wm = (wave >> 1) * 64, wn = (wave & 1) * 64;
  const int m0 = blockIdx.x * 128, n0 = blockIdx.y * 128;

  floatx4 acc[4][4] = {};

  const int sr = wave * 32 + (lane >> 2);   // staged row (this lane)
  const int sc = (lane & 3) * 8;            // staged col (shorts)
  const unsigned short* aP = A + (size_t)(m0 + sr) * K + sc;
  const unsigned short* bP = Bt + (size_t)(n0 + sr) * K + sc;
  short* asBase = &As[(wave * 32) * 32];
  short* bsBase = &Bs[(wave * 32) * 32];

  for (int k0 = 0; k0 < K; k0 += 32) {
#pragma unroll
    for (int i = 0; i < 2; ++i) {
      async_copy16(aP + (size_t)(16 * i) * K + k0, asBase + i * 512);
      async_copy16(bP + (size_t)(16 * i) * K + k0, bsBase + i * 512);
    }
    __syncthreads();   // drains vmcnt before barrier
    shortx8 af[4], bf[4];
#pragma unroll
    for (int g = 0; g < 4; ++g) {
      af[g] = *(const shortx8*)&As[(wm + g * 16 + row) * 32 + quad * 8];
      bf[g] = *(const shortx8*)&Bs[(wn + g * 16 + row) * 32 + quad * 8];
    }
#pragma unroll
    for (int mg = 0; mg < 4; ++mg)
#pragma unroll
      for (int ng = 0; ng < 4; ++ng)
        acc[mg][ng] = __builtin_amdgcn_mfma_f32_16x16x32_bf16(af[mg], bf[ng], acc[mg][ng], 0, 0, 0);
    __syncthreads();
  }

#pragma unroll
  for (int mg = 0; mg < 4; ++mg) {
    const int m = m0 + wm + mg * 16 + quad * 4;
#pragma unroll
    for (int ng = 0; ng < 4; ++ng) {
      const int n = n0 + wn + ng * 16 + row;
      const float bv = bias[n];
      const float scl = (QSCALE && n < CC) ? 0.125f : 1.0f;  // fold attn 1/sqrt(HS) into q
#pragma unroll
      for (int r = 0; r < 4; ++r) {
        const float val = (acc[mg][ng][r] + bv) * scl;
        if (OUT_BF16) ((unsigned short*)Cp)[(size_t)(m + r) * N + n] = f2bf(val);
        else          ((float*)Cp)[(size_t)(m + r) * N + n] = val;
      }
    }
  }
}

// ---------- flash attention: 128 queries/block, K-tile 64, dbuf LDS, 1 barrier/tile ----------
__global__ __launch_bounds__(256)
void attn_kernel(const unsigned short* __restrict__ qkv, const unsigned short* __restrict__ Vt,
                 unsigned short* __restrict__ y) {
  constexpr int STR = 72;
  __shared__ short Kd[2][64 * STR];   // [key][d]
  __shared__ short Vd[2][64 * STR];   // [d][key]  (from Vt)
  __shared__ short Ps[4][32 * STR];   // per-wave P scratch [q][key]

  const int qt = (int)(gridDim.x - 1 - blockIdx.x);  // heavy blocks dispatch first
  const int h = blockIdx.y, b = blockIdx.z;
  const int bh = b * NHH + h;
  const int tid = threadIdx.x, lane = tid & 63, wave = tid >> 6;
  const int row = lane & 15, quad = lane >> 4;

  const int qbase = qt * 128 + wave * 32;

  // Q fragments (A-layout, pre-scaled by 0.125 in GEMM1)
  shortx8 qf[2][2];
#pragma unroll
  for (int mf = 0; mf < 2; ++mf) {
    const unsigned short* qp = qkv + ((size_t)(b * TT) + qbase + mf * 16 + row) * QKVW + h * HSS;
    qf[mf][0] = *(const shortx8*)(qp + quad * 8);
    qf[mf][1] = *(const shortx8*)(qp + 32 + quad * 8);
  }

  float m_r[2][4], l_r[2][4];
  floatx4 o[2][4];
#pragma unroll
  for (int mf = 0; mf < 2; ++mf)
#pragma unroll
    for (int r = 0; r < 4; ++r) { m_r[mf][r] = -1e30f; l_r[mf][r] = 0.0f; }
#pragma unroll
  for (int mf = 0; mf < 2; ++mf)
#pragma unroll
    for (int g = 0; g < 4; ++g) o[mf][g] = (floatx4)(0.0f);

  const int srow = tid >> 3;        // 0..31
  const int scol = (tid & 7) * 8;
  const unsigned short* kSrc = qkv + ((size_t)(b * TT)) * QKVW + CC + h * HSS;
  const unsigned short* vSrc = Vt + ((size_t)bh * HSS) * TT;

  shortx8 kr[2], vr[2];
  // preload tile 0
#pragma unroll
  for (int i = 0; i < 2; ++i) {
    kr[i] = *(const shortx8*)(kSrc + (size_t)(srow + 32 * i) * QKVW + scol);
    vr[i] = *(const shortx8*)(vSrc + (size_t)(srow + 32 * i) * TT + scol);
  }
#pragma unroll
  for (int i = 0; i < 2; ++i) {
    *(shortx8*)&Kd[0][(srow + 32 * i) * STR + scol] = kr[i];
    *(shortx8*)&Vd[0][(srow + 32 * i) * STR + scol] = vr[i];
  }
  __syncthreads();

  const int nk = 2 * qt + 2;
  for (int kt = 0; kt < nk; ++kt) {
    const int cur = kt & 1;
    if (kt + 1 < nk) {  // register prefetch of next tile (latency hidden under compute)
#pragma unroll
      for (int i = 0; i < 2; ++i) {
        kr[i] = *(const shortx8*)(kSrc + (size_t)((kt + 1) * 64 + srow + 32 * i) * QKVW + scol);
        vr[i] = *(const shortx8*)(vSrc + (size_t)(srow + 32 * i) * TT + (kt + 1) * 64 + scol);
      }
    }
    if (kt * 64 <= qbase + 31) {   // wave-active (not fully above diagonal)
      const short* Kc = &Kd[cur][0];
      const short* Vc = &Vd[cur][0];
      // S = Q @ K^T
      floatx4 sa[2][4];
#pragma unroll
      for (int n = 0; n < 4; ++n) {
        shortx8 kf0 = *(const shortx8*)&Kc[(n * 16 + row) * STR + quad * 8];
        shortx8 kf1 = *(const shortx8*)&Kc[(n * 16 + row) * STR + 32 + quad * 8];
#pragma unroll
        for (int mf = 0; mf < 2; ++mf) {
          floatx4 t = __builtin_amdgcn_mfma_f32_16x16x32_bf16(qf[mf][0], kf0, (floatx4)(0.0f), 0, 0, 0);
          sa[mf][n] = __builtin_amdgcn_mfma_f32_16x16x32_bf16(qf[mf][1], kf1, t, 0, 0, 0);
        }
      }
      if (kt * 64 + 63 > qbase) {  // diagonal tiles: causal mask
#pragma unroll
        for (int mf = 0; mf < 2; ++mf)
#pragma unroll
          for (int n = 0; n < 4; ++n) {
            const int kg = kt * 64 + n * 16 + row;
#pragma unroll
            for (int r = 0; r < 4; ++r)
              if (kg > qbase + mf * 16 + quad * 4 + r) sa[mf][n][r] = -1e30f;
          }
      }
      // online softmax (DPP reductions over the quad's 16 lanes)
#pragma unroll
      for (int mf = 0; mf < 2; ++mf) {
        float al[4], rs[4];
#pragma unroll
        for (int r = 0; r < 4; ++r) {
          float mx = fmaxf(fmaxf(sa[mf][0][r], sa[mf][1][r]), fmaxf(sa[mf][2][r], sa[mf][3][r]));
          mx = rowmax16(mx);
          const float mn = fmaxf(m_r[mf][r], mx);
          al[r] = __expf(m_r[mf][r] - mn);
          m_r[mf][r] = mn;
          rs[r] = 0.0f;
        }
        short* pw = &Ps[wave][0];
#pragma unroll
        for (int n = 0; n < 4; ++n)
#pragma unroll
          for (int r = 0; r < 4; ++r) {
            const float p = __expf(sa[mf][n][r] - m_r[mf][r]);
            rs[r] += p;
            pw[(mf * 16 + quad * 4 + r) * STR + n * 16 + row] = (short)bfp(p);
          }
#pragma unroll
        for (int r = 0; r < 4; ++r) {
          rs[r] = rowsum16(rs[r]);
          l_r[mf][r] = l_r[mf][r] * al[r] + rs[r];
        }
#pragma unroll
        for (int g = 0; g < 4; ++g) {
          floatx4 t = o[mf][g];
          t[0] *= al[0]; t[1] *= al[1]; t[2] *= al[2]; t[3] *= al[3];
          o[mf][g] = t;
        }
      }
      // O += P @ V   (P round-trip is per-wave: no barrier needed)
#pragma unroll
      for (int c = 0; c < 2; ++c) {
        shortx8 pf0 = *(const shortx8*)&Ps[wave][(row) * STR + c * 32 + quad * 8];
        shortx8 pf1 = *(const shortx8*)&Ps[wave][(16 + row) * STR + c * 32 + quad * 8];
#pragma unroll
        for (int g = 0; g < 4; ++g) {
          shortx8 vf = *(const shortx8*)&Vc[(g * 16 + row) * STR + c * 32 + quad * 8];
          o[0][g] = __builtin_amdgcn_mfma_f32_16x16x32_bf16(pf0, vf, o[0][g], 0, 0, 0);
          o[1][g] = __builtin_amdgcn_mfma_f32_16x16x32_bf16(pf1, vf, o[1][g], 0, 0, 0);
        }
      }
    }
    if (kt + 1 < nk) {  // stash prefetch into the other buffer (no reader there)
      const int nb = (kt + 1) & 1;
#pragma unroll
      for (int i = 0; i < 2; ++i) {
        *(shortx8*)&Kd[nb][(srow + 32 * i) * STR + scol] = kr[i];
        *(shortx8*)&Vd[nb][(srow + 32 * i) * STR + scol] = vr[i];
      }
    }
    __syncthreads();  // single barrier per tile
  }

  // epilogue
#pragma unroll
  for (int mf = 0; mf < 2; ++mf)
#pragma unroll
    for (int r = 0; r < 4; ++r) {
      const float inv = 1.0f / l_r[mf][r];
      unsigned short* yp = y + ((size_t)(b * TT) + qbase + mf * 16 + quad * 4 + r) * CC + h * HSS;
#pragma unroll
      for (int g = 0; g < 4; ++g)
        yp[g * 16 + row] = bfp(o[mf][g][r] * inv);
    }
}

extern "C" void kernel_launch(void* const* d_in, const int* in_sizes, int n_in,
                              void* d_out, int out_size, void* d_ws, size_t ws_size,
                              hipStream_t stream) {
  const float* x      = (const float*)d_in[0];
  const float* w_attn = (const float*)d_in[1];
  const float* b_attn = (const float*)d_in[2];
  const float* w_proj = (const float*)d_in[3];
  const float* b_proj = (const float*)d_in[4];
  float* out = (float*)d_out;

  // workspace layout (61.2 MiB):
  //   [0, 12.6M)        xb (x as bf16; dead after GEMM1)  -> reused as y
  //   [12.6M, 50.3M)    qkv bf16 [8192][2304]
  //   [50.3M, 62.9M)    wta bf16 [2304][768] (dead after GEMM1) overlaid by Vt [48][64][2048]
  //   [62.9M, 64.1M)    wtp bf16 [768][768]
  char* ws = (char*)d_ws;
  unsigned short* xb  = (unsigned short*)ws;
  unsigned short* y   = (unsigned short*)ws;                          // reuse after GEMM1
  unsigned short* qkv = (unsigned short*)(ws + 12582912);
  unsigned short* wta = (unsigned short*)(ws + 50331648);
  unsigned short* Vt  = (unsigned short*)(ws + 50331648);             // overlays wta post-GEMM1
  unsigned short* wtp = (unsigned short*)(ws + 62914560);

  const int M = BB * TT;  // 8192

  convert_x<<<1024, 256, 0, stream>>>(x, xb, (M * CC) / 4);
  transpose_w<<<dim3(QKVW / 64, CC / 64), 256, 0, stream>>>(w_attn, wta, CC, QKVW);
  transpose_w<<<dim3(CC / 64, CC / 64), 256, 0, stream>>>(w_proj, wtp, CC, CC);

  gemm_tn<true, true><<<dim3(M / 128, QKVW / 128), 256, 0, stream>>>(
      xb, wta, b_attn, (void*)qkv, M, QKVW, CC);

  transpose_v<<<dim3(TT / 64, BB * NHH), 256, 0, stream>>>(qkv, Vt);

  attn_kernel<<<dim3(TT / 128, NHH, BB), 256, 0, stream>>>(qkv, Vt, y);

  gemm_tn<false, false><<<dim3(M / 128, CC / 128), 256, 0, stream>>>(
      y, wtp, b_proj, (void*)out, M, CC, CC);
}